// Round 1
// baseline (1536.560 us; speedup 1.0000x reference)
//
#include <hip/hip_runtime.h>
#include <math.h>

#define BATCH 4
#define SEQ   4096
#define DIM   1024
#define HEAD  64
#define MROWS (BATCH * SEQ)   // 16384

// ---------------- Kernel 1: QKV projection (fp32 tiled GEMM) ----------------
// grid (MROWS/64, 3), block 256. blockIdx.y selects q/k/v.
__global__ __launch_bounds__(256) void qkv_kernel(
    const float* __restrict__ x,
    const float* __restrict__ wq, const float* __restrict__ bq,
    const float* __restrict__ wk, const float* __restrict__ bk,
    const float* __restrict__ wv, const float* __restrict__ bv,
    float* __restrict__ qout, float* __restrict__ kout, float* __restrict__ vout)
{
    const int which = blockIdx.y;
    const float* __restrict__ w    = (which == 0) ? wq : (which == 1) ? wk : wv;
    const float* __restrict__ bias = (which == 0) ? bq : (which == 1) ? bk : bv;
    float* __restrict__ out        = (which == 0) ? qout : (which == 1) ? kout : vout;
    const float scale = (which == 0) ? 0.125f : 1.0f;   // fold 1/sqrt(64) into q

    __shared__ float xs[32][64 + 4];    // [k][row], stride 68 floats (16B-aligned rows)
    __shared__ float ws2[32][64 + 4];   // [k][col]

    const int tid = threadIdx.x;
    const int m0 = blockIdx.x * 64;
    const int tx = tid & 15;            // col group
    const int ty = tid >> 4;            // row group

    float acc[4][4] = {};

    for (int ko = 0; ko < DIM; ko += 32) {
        #pragma unroll
        for (int i = 0; i < 2; ++i) {
            int fi  = tid + i * 256;    // 0..511 float4s
            int row = fi >> 3;          // 8 float4 per row (32 floats)
            int c4  = fi & 7;
            float4 g = *(const float4*)&x[(size_t)(m0 + row) * DIM + ko + c4 * 4];
            xs[c4 * 4 + 0][row] = g.x; xs[c4 * 4 + 1][row] = g.y;
            xs[c4 * 4 + 2][row] = g.z; xs[c4 * 4 + 3][row] = g.w;
        }
        #pragma unroll
        for (int i = 0; i < 2; ++i) {
            int fi  = tid + i * 256;
            int col = fi >> 3;
            int c4  = fi & 7;
            float4 g = *(const float4*)&w[(size_t)col * DIM + ko + c4 * 4];
            ws2[c4 * 4 + 0][col] = g.x; ws2[c4 * 4 + 1][col] = g.y;
            ws2[c4 * 4 + 2][col] = g.z; ws2[c4 * 4 + 3][col] = g.w;
        }
        __syncthreads();
        #pragma unroll
        for (int kk = 0; kk < 32; ++kk) {
            float4 a = *(const float4*)&xs[kk][ty * 4];
            float4 b = *(const float4*)&ws2[kk][tx * 4];
            float av[4] = {a.x, a.y, a.z, a.w};
            float bw[4] = {b.x, b.y, b.z, b.w};
            #pragma unroll
            for (int i = 0; i < 4; ++i)
                #pragma unroll
                for (int j = 0; j < 4; ++j)
                    acc[i][j] += av[i] * bw[j];
        }
        __syncthreads();
    }

    #pragma unroll
    for (int i = 0; i < 4; ++i) {
        int row = m0 + ty * 4 + i;
        float4 o;
        o.x = (acc[i][0] + bias[tx * 4 + 0]) * scale;
        o.y = (acc[i][1] + bias[tx * 4 + 1]) * scale;
        o.z = (acc[i][2] + bias[tx * 4 + 2]) * scale;
        o.w = (acc[i][3] + bias[tx * 4 + 3]) * scale;
        *(float4*)&out[(size_t)row * HEAD + tx * 4] = o;
    }
}

// ---------------- Kernel 2: flash attention (fp32) ----------------
// grid (SEQ/32, BATCH), block 256 (4 waves). 32 query rows/block, 64-key tiles.
#define QT 32
#define KT 64

__global__ __launch_bounds__(256) void flash_kernel(
    const float* __restrict__ q, const float* __restrict__ k,
    const float* __restrict__ v, const int* __restrict__ mask,
    float* __restrict__ out)
{
    const int b  = blockIdx.y;
    const int t0 = blockIdx.x * QT;
    const int tid = threadIdx.x;

    __shared__ float qs[QT][HEAD];       // broadcast-only reads
    __shared__ float ks[KT][HEAD + 4];   // stride 68: b128 reads spread over all banks
    __shared__ float vs[KT][HEAD + 4];
    __shared__ float ps[QT][KT + 4];
    __shared__ float sf_lds[QT];
    __shared__ float l_lds[QT];
    __shared__ int   mk[KT];

    const float* __restrict__ qb = q + ((size_t)b * SEQ + t0) * HEAD;
    const float* __restrict__ kb = k + (size_t)b * SEQ * HEAD;
    const float* __restrict__ vb = v + (size_t)b * SEQ * HEAD;

    // load q tile: 32x64 floats = 512 float4
    #pragma unroll
    for (int i = 0; i < 2; ++i) {
        int fi  = tid + i * 256;
        int row = fi >> 4;               // 16 float4 per row
        int c4  = fi & 15;
        *(float4*)&qs[row][c4 * 4] = *(const float4*)&qb[(size_t)row * HEAD + c4 * 4];
    }

    // score-phase mapping: lane = key index, wave wy owns rows {wy, wy+4, ..., wy+28}
    const int s_ = tid & 63;
    const int wy = tid >> 6;
    // PV-phase mapping: 4 h-columns per thread, rows rg and rg+16
    const int hq = (tid & 15) * 4;
    const int rg = tid >> 4;

    float m_r[8], l_r[8];
    #pragma unroll
    for (int i = 0; i < 8; ++i) { m_r[i] = -INFINITY; l_r[i] = 0.f; }
    float o0x = 0, o0y = 0, o0z = 0, o0w = 0;
    float o1x = 0, o1y = 0, o1z = 0, o1w = 0;

    for (int st = 0; st < SEQ; st += KT) {
        __syncthreads();   // previous PV done reading vs/ps before overwrite
        #pragma unroll
        for (int i = 0; i < 4; ++i) {
            int fi  = tid + i * 256;     // 0..1023 float4
            int row = fi >> 4;
            int c4  = fi & 15;
            *(float4*)&ks[row][c4 * 4] = *(const float4*)&kb[(size_t)(st + row) * HEAD + c4 * 4];
            *(float4*)&vs[row][c4 * 4] = *(const float4*)&vb[(size_t)(st + row) * HEAD + c4 * 4];
        }
        if (tid < KT) mk[tid] = mask[(size_t)b * SEQ + st + tid];
        __syncthreads();

        // ---- scores: S[r][s_] for r = wy + 4i ----
        float sc[8];
        #pragma unroll
        for (int i = 0; i < 8; ++i) sc[i] = 0.f;
        #pragma unroll
        for (int h4 = 0; h4 < 16; ++h4) {
            float4 kk4 = *(const float4*)&ks[s_][h4 * 4];
            #pragma unroll
            for (int i = 0; i < 8; ++i) {
                int r = wy + 4 * i;
                float4 q4 = *(const float4*)&qs[r][h4 * 4];   // broadcast
                sc[i] += q4.x * kk4.x + q4.y * kk4.y + q4.z * kk4.z + q4.w * kk4.w;
            }
        }
        const bool keep = (mk[s_] != 0);

        #pragma unroll
        for (int i = 0; i < 8; ++i) {
            float x_ = keep ? sc[i] : -1e9f;
            float mx = x_;
            #pragma unroll
            for (int off = 32; off; off >>= 1) mx = fmaxf(mx, __shfl_xor(mx, off));
            float m_new = fmaxf(m_r[i], mx);
            float w_ = __expf(x_ - m_new);
            float wsum = w_;
            #pragma unroll
            for (int off = 32; off; off >>= 1) wsum += __shfl_xor(wsum, off);
            float sf = __expf(m_r[i] - m_new);   // -inf -> 0 on first tile
            l_r[i] = l_r[i] * sf + wsum;
            m_r[i] = m_new;
            int r = wy + 4 * i;
            ps[r][s_] = w_;
            if (s_ == 0) sf_lds[r] = sf;
        }
        __syncthreads();

        // ---- PV: o[r][hq..hq+3] += sum_s P[r][s] * v[s][hq..] ----
        float sfa = sf_lds[rg], sfb = sf_lds[rg + 16];
        o0x *= sfa; o0y *= sfa; o0z *= sfa; o0w *= sfa;
        o1x *= sfb; o1y *= sfb; o1z *= sfb; o1w *= sfb;
        #pragma unroll
        for (int s4 = 0; s4 < KT; s4 += 4) {
            float4 va = *(const float4*)&vs[s4 + 0][hq];
            float4 vb4 = *(const float4*)&vs[s4 + 1][hq];
            float4 vc = *(const float4*)&vs[s4 + 2][hq];
            float4 vd = *(const float4*)&vs[s4 + 3][hq];
            float4 pa = *(const float4*)&ps[rg][s4];
            float4 pb = *(const float4*)&ps[rg + 16][s4];
            o0x += pa.x * va.x + pa.y * vb4.x + pa.z * vc.x + pa.w * vd.x;
            o0y += pa.x * va.y + pa.y * vb4.y + pa.z * vc.y + pa.w * vd.y;
            o0z += pa.x * va.z + pa.y * vb4.z + pa.z * vc.z + pa.w * vd.z;
            o0w += pa.x * va.w + pa.y * vb4.w + pa.z * vc.w + pa.w * vd.w;
            o1x += pb.x * va.x + pb.y * vb4.x + pb.z * vc.x + pb.w * vd.x;
            o1y += pb.x * va.y + pb.y * vb4.y + pb.z * vc.y + pb.w * vd.y;
            o1z += pb.x * va.z + pb.y * vb4.z + pb.z * vc.z + pb.w * vd.z;
            o1w += pb.x * va.w + pb.y * vb4.w + pb.z * vc.w + pb.w * vd.w;
        }
    }

    // publish l (score-phase layout) -> PV-phase layout
    __syncthreads();
    if (s_ == 0) {
        #pragma unroll
        for (int i = 0; i < 8; ++i) l_lds[wy + 4 * i] = l_r[i];
    }
    __syncthreads();

    float la = l_lds[rg], lb = l_lds[rg + 16];
    float ra = 1.0f / la, rb = 1.0f / lb;
    float4 r0, r1;
    r0.x = o0x * ra; r0.y = o0y * ra; r0.z = o0z * ra; r0.w = o0w * ra;
    r1.x = o1x * rb; r1.y = o1y * rb; r1.z = o1z * rb; r1.w = o1w * rb;
    *(float4*)&out[((size_t)b * SEQ + t0 + rg) * HEAD + hq] = r0;
    *(float4*)&out[((size_t)b * SEQ + t0 + rg + 16) * HEAD + hq] = r1;
}

extern "C" void kernel_launch(void* const* d_in, const int* in_sizes, int n_in,
                              void* d_out, int out_size, void* d_ws, size_t ws_size,
                              hipStream_t stream) {
    const float* x    = (const float*)d_in[0];
    const int*   mask = (const int*)d_in[1];
    const float* wq   = (const float*)d_in[2];
    const float* bq   = (const float*)d_in[3];
    const float* wk   = (const float*)d_in[4];
    const float* bk   = (const float*)d_in[5];
    const float* wv   = (const float*)d_in[6];
    const float* bv   = (const float*)d_in[7];
    float* out = (float*)d_out;

    float* qw = (float*)d_ws;                       // MROWS*HEAD fp32 (4 MB)
    float* kw = qw + (size_t)MROWS * HEAD;
    float* vw = kw + (size_t)MROWS * HEAD;
    (void)in_sizes; (void)n_in; (void)out_size; (void)ws_size;

    qkv_kernel<<<dim3(MROWS / 64, 3), 256, 0, stream>>>(x, wq, bq, wk, bk, wv, bv, qw, kw, vw);
    flash_kernel<<<dim3(SEQ / QT, BATCH), 256, 0, stream>>>(qw, kw, vw, mask, out);
}

// Round 2
// 164.638 us; speedup vs baseline: 9.3330x; 9.3330x over previous
//
#include <hip/hip_runtime.h>
#include <math.h>

#define BATCH 4
#define SEQ   4096
#define DIM   1024
#define HEAD  64
#define MROWS (BATCH*SEQ)   // 16384
#define KT    64
#define QBLK  64

typedef __attribute__((ext_vector_type(8))) short short8;
typedef __attribute__((ext_vector_type(4))) float f32x4;

static __device__ __forceinline__ unsigned short f2b(float f) {
    union { float f; unsigned u; } v; v.f = f;
    return (unsigned short)((v.u + 0x7FFFu + ((v.u >> 16) & 1u)) >> 16);
}

// ---------------- Kernel 1: QKV projection (fp32 compute, bf16 out) ----------------
// grid (MROWS/64, 3), block 256. y=0: q (scaled 0.125), y=1: k, y=2: v transposed [B][H][T].
__global__ __launch_bounds__(256) void qkv_kernel(
    const float* __restrict__ x,
    const float* __restrict__ wq, const float* __restrict__ bq,
    const float* __restrict__ wk, const float* __restrict__ bk,
    const float* __restrict__ wv, const float* __restrict__ bv,
    unsigned short* __restrict__ qout, unsigned short* __restrict__ kout,
    unsigned short* __restrict__ vtout)
{
    const int which = blockIdx.y;
    const float* __restrict__ w    = (which == 0) ? wq : (which == 1) ? wk : wv;
    const float* __restrict__ bias = (which == 0) ? bq : (which == 1) ? bk : bv;
    const float scale = (which == 0) ? 0.125f : 1.0f;   // fold 1/sqrt(64) into q

    __shared__ float xs[32][64 + 4];
    __shared__ float ws2[32][64 + 4];

    const int tid = threadIdx.x;
    const int m0 = blockIdx.x * 64;
    const int tx = tid & 15;
    const int ty = tid >> 4;

    float acc[4][4] = {};

    for (int ko = 0; ko < DIM; ko += 32) {
        #pragma unroll
        for (int i = 0; i < 2; ++i) {
            int fi  = tid + i * 256;
            int row = fi >> 3;
            int c4  = fi & 7;
            float4 g = *(const float4*)&x[(size_t)(m0 + row) * DIM + ko + c4 * 4];
            xs[c4 * 4 + 0][row] = g.x; xs[c4 * 4 + 1][row] = g.y;
            xs[c4 * 4 + 2][row] = g.z; xs[c4 * 4 + 3][row] = g.w;
        }
        #pragma unroll
        for (int i = 0; i < 2; ++i) {
            int fi  = tid + i * 256;
            int col = fi >> 3;
            int c4  = fi & 7;
            float4 g = *(const float4*)&w[(size_t)col * DIM + ko + c4 * 4];
            ws2[c4 * 4 + 0][col] = g.x; ws2[c4 * 4 + 1][col] = g.y;
            ws2[c4 * 4 + 2][col] = g.z; ws2[c4 * 4 + 3][col] = g.w;
        }
        __syncthreads();
        #pragma unroll
        for (int kk = 0; kk < 32; ++kk) {
            float4 a = *(const float4*)&xs[kk][ty * 4];
            float4 b = *(const float4*)&ws2[kk][tx * 4];
            float av[4] = {a.x, a.y, a.z, a.w};
            float bw[4] = {b.x, b.y, b.z, b.w};
            #pragma unroll
            for (int i = 0; i < 4; ++i)
                #pragma unroll
                for (int j = 0; j < 4; ++j)
                    acc[i][j] += av[i] * bw[j];
        }
        __syncthreads();
    }

    if (which < 2) {
        unsigned short* __restrict__ ob = (which == 0) ? qout : kout;
        #pragma unroll
        for (int i = 0; i < 4; ++i) {
            int row = m0 + ty * 4 + i;
            ushort4 o4;
            o4.x = f2b((acc[i][0] + bias[tx * 4 + 0]) * scale);
            o4.y = f2b((acc[i][1] + bias[tx * 4 + 1]) * scale);
            o4.z = f2b((acc[i][2] + bias[tx * 4 + 2]) * scale);
            o4.w = f2b((acc[i][3] + bias[tx * 4 + 3]) * scale);
            *(ushort4*)&ob[(size_t)row * HEAD + tx * 4] = o4;
        }
    } else {
        // transpose 64x64 tile through LDS, write Vt[b][h][t] bf16
        unsigned short* tb = (unsigned short*)&xs[0][0];   // 8KB <= xs size
        #pragma unroll
        for (int i = 0; i < 4; ++i)
            #pragma unroll
            for (int j = 0; j < 4; ++j)
                tb[(tx * 4 + j) * 64 + (ty * 4 + i)] = f2b(acc[i][j] + bias[tx * 4 + j]);
        __syncthreads();
        const int bb = m0 / SEQ;
        const int trow0 = m0 - bb * SEQ;
        const int col = tid >> 2, part = tid & 3;
        short8 a0 = *(short8*)&tb[col * 64 + part * 16];
        short8 a1 = *(short8*)&tb[col * 64 + part * 16 + 8];
        unsigned short* dst = vtout + ((size_t)bb * HEAD + col) * SEQ + trow0 + part * 16;
        *(short8*)dst = a0;
        *(short8*)(dst + 8) = a1;
    }
}

// ---------------- Kernel 2: flash attention, bf16 MFMA ----------------
// grid (SEQ/QBLK, BATCH, KS). block 256 (4 waves); wave w owns q rows [t0+16w, t0+16w+16).
__global__ __launch_bounds__(256, 4) void flashmm_kernel(
    const unsigned short* __restrict__ qb, const unsigned short* __restrict__ kb,
    const unsigned short* __restrict__ vt, const int* __restrict__ mask,
    float* __restrict__ opart, float* __restrict__ mpart, float* __restrict__ lpart,
    int nsplit)
{
    const int b  = blockIdx.y;
    const int t0 = blockIdx.x * QBLK;
    const int z  = blockIdx.z;
    const int tid  = threadIdx.x;
    const int lane = tid & 63;
    const int w    = tid >> 6;
    const int lr = lane & 15;      // frag row (A) / col (B,D)
    const int lg = lane >> 4;      // k-group
    const int span = SEQ / nsplit;
    const int s_begin = z * span, s_end = s_begin + span;

    __shared__ unsigned short ks_l[KT * HEAD];     // swizzled [krow][h]
    __shared__ unsigned short vt_l[HEAD * KT];     // swizzled [h][s]
    __shared__ unsigned short ps_l[4][16 * KT];    // per-wave swizzled [qr][s]
    __shared__ int mk[KT];

    // Q fragments (persistent): lane lr -> q row, lg -> h-chunk
    const unsigned short* qrow = qb + ((size_t)(b * SEQ + t0 + w * 16 + lr)) * HEAD;
    const short8 qf0 = *(const short8*)(qrow + lg * 8);
    const short8 qf1 = *(const short8*)(qrow + 32 + lg * 8);

    f32x4 acc_o[4];
    #pragma unroll
    for (int nt = 0; nt < 4; ++nt) acc_o[nt] = (f32x4){0.f, 0.f, 0.f, 0.f};
    float m_r[4] = {-INFINITY, -INFINITY, -INFINITY, -INFINITY};
    float l_r[4] = {0.f, 0.f, 0.f, 0.f};

    for (int st = s_begin; st < s_end; st += KT) {
        __syncthreads();
        #pragma unroll
        for (int i = 0; i < 2; ++i) {
            int c   = tid + i * 256;      // 0..511
            int row = c >> 3;
            int h0  = (c & 7) * 8;
            short8 gk = *(const short8*)(kb + ((size_t)(b * SEQ + st + row)) * HEAD + h0);
            *(short8*)&ks_l[row * HEAD + (h0 ^ ((row & 7) << 3))] = gk;
            short8 gv = *(const short8*)(vt + ((size_t)(b * HEAD + row)) * SEQ + st + h0);
            *(short8*)&vt_l[row * KT + (h0 ^ ((row & 7) << 3))] = gv;
        }
        if (tid < KT) mk[tid] = mask[(size_t)b * SEQ + st + tid];
        __syncthreads();

        // ---- QK^T: 4 col-tiles x (K=64 via 2 MFMA) ----
        f32x4 s_acc[4];
        #pragma unroll
        for (int ct = 0; ct < 4; ++ct) {
            int krow = ct * 16 + lr;
            short8 kf0 = *(const short8*)&ks_l[krow * HEAD + ((lg * 8) ^ ((krow & 7) << 3))];
            short8 kf1 = *(const short8*)&ks_l[krow * HEAD + ((32 + lg * 8) ^ ((krow & 7) << 3))];
            f32x4 zz = (f32x4){0.f, 0.f, 0.f, 0.f};
            zz = __builtin_amdgcn_mfma_f32_16x16x32_bf16(qf0, kf0, zz, 0, 0, 0);
            zz = __builtin_amdgcn_mfma_f32_16x16x32_bf16(qf1, kf1, zz, 0, 0, 0);
            s_acc[ct] = zz;
        }

        bool kp[4];
        #pragma unroll
        for (int ct = 0; ct < 4; ++ct) kp[ct] = (mk[ct * 16 + lr] != 0);

        // ---- online softmax (rows R = lg*4 + r) ----
        float sf[4];
        #pragma unroll
        for (int r = 0; r < 4; ++r) {
            float v0 = kp[0] ? s_acc[0][r] : -1e9f;
            float v1 = kp[1] ? s_acc[1][r] : -1e9f;
            float v2 = kp[2] ? s_acc[2][r] : -1e9f;
            float v3 = kp[3] ? s_acc[3][r] : -1e9f;
            float mx = fmaxf(fmaxf(v0, v1), fmaxf(v2, v3));
            #pragma unroll
            for (int off = 1; off < 16; off <<= 1) mx = fmaxf(mx, __shfl_xor(mx, off));
            float mnew = fmaxf(m_r[r], mx);
            float p0 = __expf(v0 - mnew), p1 = __expf(v1 - mnew);
            float p2 = __expf(v2 - mnew), p3 = __expf(v3 - mnew);
            float rs = p0 + p1 + p2 + p3;
            #pragma unroll
            for (int off = 1; off < 16; off <<= 1) rs += __shfl_xor(rs, off);
            float sfr = __expf(m_r[r] - mnew);
            l_r[r] = l_r[r] * sfr + rs;
            m_r[r] = mnew;
            sf[r]  = sfr;
            int R = lg * 4 + r;
            unsigned short* pr = &ps_l[w][R * KT];
            int sw = (R & 7) << 3;
            pr[(0 * 16 + lr) ^ sw] = f2b(p0);
            pr[(1 * 16 + lr) ^ sw] = f2b(p1);
            pr[(2 * 16 + lr) ^ sw] = f2b(p2);
            pr[(3 * 16 + lr) ^ sw] = f2b(p3);
        }

        // rescale O accumulators (same row layout as D)
        #pragma unroll
        for (int nt = 0; nt < 4; ++nt) {
            acc_o[nt][0] *= sf[0]; acc_o[nt][1] *= sf[1];
            acc_o[nt][2] *= sf[2]; acc_o[nt][3] *= sf[3];
        }

        // ---- PV: A = P [16 x KT], B = V [KT x 64] via Vt rows ----
        #pragma unroll
        for (int kk = 0; kk < 2; ++kk) {
            int s0 = kk * 32 + lg * 8;
            short8 pf = *(const short8*)&ps_l[w][lr * KT + (s0 ^ ((lr & 7) << 3))];
            #pragma unroll
            for (int nt = 0; nt < 4; ++nt) {
                int hrow = nt * 16 + lr;
                short8 vf = *(const short8*)&vt_l[hrow * KT + (s0 ^ ((hrow & 7) << 3))];
                acc_o[nt] = __builtin_amdgcn_mfma_f32_16x16x32_bf16(pf, vf, acc_o[nt], 0, 0, 0);
            }
        }
    }

    // ---- write unnormalized partials ----
    const size_t rbase = (size_t)z * MROWS + (size_t)b * SEQ + t0 + w * 16;
    const size_t obase = rbase * HEAD;
    #pragma unroll
    for (int nt = 0; nt < 4; ++nt)
        #pragma unroll
        for (int r = 0; r < 4; ++r) {
            int R = lg * 4 + r;
            opart[obase + (size_t)R * HEAD + nt * 16 + lr] = acc_o[nt][r];
        }
    if (lr == 0) {
        #pragma unroll
        for (int r = 0; r < 4; ++r) {
            int R = lg * 4 + r;
            mpart[rbase + R] = m_r[r];
            lpart[rbase + R] = l_r[r];
        }
    }
}

// ---------------- Kernel 3: split combine + normalize ----------------
__global__ __launch_bounds__(256) void combine_kernel(
    const float* __restrict__ op, const float* __restrict__ mp,
    const float* __restrict__ lp, float* __restrict__ out, int nsplit)
{
    int idx = blockIdx.x * 256 + threadIdx.x;     // MROWS*16 threads
    int row = idx >> 4;
    int h4  = (idx & 15) * 4;
    float mstar = -INFINITY;
    for (int s = 0; s < nsplit; ++s)
        mstar = fmaxf(mstar, mp[(size_t)s * MROWS + row]);
    float L = 0.f;
    float ax = 0.f, ay = 0.f, az = 0.f, aw = 0.f;
    for (int s = 0; s < nsplit; ++s) {
        float wgt = __expf(mp[(size_t)s * MROWS + row] - mstar);
        L += lp[(size_t)s * MROWS + row] * wgt;
        float4 o = *(const float4*)&op[((size_t)s * MROWS + row) * HEAD + h4];
        ax += o.x * wgt; ay += o.y * wgt; az += o.z * wgt; aw += o.w * wgt;
    }
    float r = 1.f / L;
    float4 res; res.x = ax * r; res.y = ay * r; res.z = az * r; res.w = aw * r;
    *(float4*)&out[(size_t)row * HEAD + h4] = res;
}

extern "C" void kernel_launch(void* const* d_in, const int* in_sizes, int n_in,
                              void* d_out, int out_size, void* d_ws, size_t ws_size,
                              hipStream_t stream) {
    const float* x    = (const float*)d_in[0];
    const int*   mask = (const int*)d_in[1];
    const float* wq   = (const float*)d_in[2];
    const float* bq   = (const float*)d_in[3];
    const float* wk   = (const float*)d_in[4];
    const float* bk   = (const float*)d_in[5];
    const float* wv   = (const float*)d_in[6];
    const float* bv   = (const float*)d_in[7];
    float* out = (float*)d_out;
    (void)in_sizes; (void)n_in; (void)out_size;

    const size_t NB = (size_t)MROWS * HEAD;       // 1,048,576 elements
    unsigned short* qw = (unsigned short*)d_ws;   // bf16
    unsigned short* kw = qw + NB;
    unsigned short* vtw = kw + NB;
    float* mpart = (float*)(vtw + NB);

    // need(K) = 6 MB bf16 + K*(MROWS*8 + NB*4) bytes
    const size_t base = 3 * NB * 2;
    const size_t per  = (size_t)MROWS * 8 + NB * 4;
    int KS = 1;
    if (ws_size >= base + 4 * per) KS = 4;
    else if (ws_size >= base + 2 * per) KS = 2;

    float* lpart = mpart + (size_t)KS * MROWS;
    float* opart = lpart + (size_t)KS * MROWS;

    qkv_kernel<<<dim3(MROWS / 64, 3), 256, 0, stream>>>(x, wq, bq, wk, bk, wv, bv, qw, kw, vtw);
    flashmm_kernel<<<dim3(SEQ / QBLK, BATCH, KS), 256, 0, stream>>>(qw, kw, vtw, mask,
                                                                    opart, mpart, lpart, KS);
    combine_kernel<<<dim3(MROWS * 16 / 256), 256, 0, stream>>>(opart, mpart, lpart, out, KS);
}

// Round 3
// 95.193 us; speedup vs baseline: 16.1416x; 1.7295x over previous
//
#include <hip/hip_runtime.h>
#include <math.h>

#define BATCH 4
#define SEQ   4096
#define DIM   1024
#define HEAD  64
#define MROWS (BATCH*SEQ)   // 16384
#define KT    64
#define QBLK  64

typedef __attribute__((ext_vector_type(8))) short short8;
typedef __attribute__((ext_vector_type(4))) float f32x4;

static __device__ __forceinline__ unsigned short f2b(float f) {
    union { float f; unsigned u; } v; v.f = f;
    return (unsigned short)((v.u + 0x7FFFu + ((v.u >> 16) & 1u)) >> 16);
}

// ---------------- Kernel 0: weight convert fp32 -> bf16 [192][1024], q-scale folded ----
__global__ __launch_bounds__(256) void wconv_kernel(
    const float* __restrict__ wq, const float* __restrict__ bq,
    const float* __restrict__ wk, const float* __restrict__ bk,
    const float* __restrict__ wv, const float* __restrict__ bv,
    unsigned short* __restrict__ Wb, float* __restrict__ biasAll)
{
    int idx = blockIdx.x * 256 + threadIdx.x;   // 49152 threads, 4 elts each
    int e   = idx * 4;
    int row = e >> 10;
    int col = e & 1023;
    const float* src = (row < 64) ? wq : (row < 128) ? wk : wv;
    float s = (row < 64) ? 0.125f : 1.0f;
    float4 g = *(const float4*)&src[(size_t)(row & 63) * DIM + col];
    ushort4 o;
    o.x = f2b(g.x * s); o.y = f2b(g.y * s); o.z = f2b(g.z * s); o.w = f2b(g.w * s);
    *(ushort4*)&Wb[e] = o;
    if (idx < 192) {
        const float* bs = (idx < 64) ? bq : (idx < 128) ? bk : bv;
        biasAll[idx] = bs[idx & 63] * ((idx < 64) ? 0.125f : 1.0f);
    }
}

// ---------------- Kernel 1: fused QKV projection, bf16 MFMA ----------------
// M=16384, N=192, K=1024. grid 512 (BM=32), block 256.
// wave w: rows (w>>1)*16..+16, n-tiles (w&1)*6..+6. T3-min pipeline, 2 LDS buffers.
#define NIT (DIM / 32)
__global__ __launch_bounds__(256) void qkvmm_kernel(
    const float* __restrict__ x, const unsigned short* __restrict__ Wb,
    const float* __restrict__ biasAll,
    unsigned short* __restrict__ qout, unsigned short* __restrict__ kout,
    unsigned short* __restrict__ vtout)
{
    __shared__ unsigned short xs[2][32 * 32];    // 2 KB each, swizzled
    __shared__ unsigned short ws[2][192 * 32];   // 12 KB each, swizzled

    const int tid  = threadIdx.x;
    const int m0   = blockIdx.x * 32;
    const int bb   = m0 >> 12;                   // batch (SEQ=4096)
    const int lane = tid & 63;
    const int w    = tid >> 6;
    const int lr   = lane & 15;
    const int lg   = lane >> 4;
    const int mrow  = (w >> 1) * 16;
    const int nbase = (w & 1) * 6;

    // staging assignments (x: threads 0..127; W: all, 3 chunks)
    const int sxrow = tid >> 2, sxlg = tid & 3;  // valid when tid<128
    int wn[3], wlg[3];
    #pragma unroll
    for (int i = 0; i < 3; ++i) { int idx = tid + i * 256; wn[i] = idx >> 2; wlg[i] = idx & 3; }

    f32x4 acc[6];
    #pragma unroll
    for (int nt = 0; nt < 6; ++nt) acc[nt] = (f32x4){0.f, 0.f, 0.f, 0.f};

    float4 xg0, xg1;
    short8 wg[3];

    auto LOADR = [&](int ko) {
        if (tid < 128) {
            const float* xp = &x[(size_t)(m0 + sxrow) * DIM + ko + sxlg * 8];
            xg0 = *(const float4*)xp;
            xg1 = *(const float4*)(xp + 4);
        }
        #pragma unroll
        for (int i = 0; i < 3; ++i)
            wg[i] = *(const short8*)&Wb[(size_t)wn[i] * DIM + ko + wlg[i] * 8];
    };
    auto WRITE = [&](int buf) {
        if (tid < 128) {
            short8 c;
            c[0] = (short)f2b(xg0.x); c[1] = (short)f2b(xg0.y);
            c[2] = (short)f2b(xg0.z); c[3] = (short)f2b(xg0.w);
            c[4] = (short)f2b(xg1.x); c[5] = (short)f2b(xg1.y);
            c[6] = (short)f2b(xg1.z); c[7] = (short)f2b(xg1.w);
            *(short8*)&xs[buf][sxrow * 32 + ((sxlg * 8) ^ ((sxrow & 3) * 8))] = c;
        }
        #pragma unroll
        for (int i = 0; i < 3; ++i)
            *(short8*)&ws[buf][wn[i] * 32 + ((wlg[i] * 8) ^ ((wn[i] & 3) * 8))] = wg[i];
    };

    LOADR(0);
    WRITE(0);
    __syncthreads();

    for (int it = 0; it < NIT; ++it) {
        if (it + 1 < NIT) LOADR((it + 1) * 32);          // issue-early
        const int cur = it & 1;
        const int arow = mrow + lr;
        short8 af = *(const short8*)&xs[cur][arow * 32 + ((lg * 8) ^ ((arow & 3) * 8))];
        #pragma unroll
        for (int nt = 0; nt < 6; ++nt) {
            int n = (nbase + nt) * 16 + lr;
            short8 bf = *(const short8*)&ws[cur][n * 32 + ((lg * 8) ^ ((n & 3) * 8))];
            acc[nt] = __builtin_amdgcn_mfma_f32_16x16x32_bf16(af, bf, acc[nt], 0, 0, 0);
        }
        if (it + 1 < NIT) WRITE((it + 1) & 1);           // write-late, other buffer
        __syncthreads();
    }

    // epilogue: add bias, bf16, scatter to q / k / vt
    #pragma unroll
    for (int nt = 0; nt < 6; ++nt) {
        int gn = (nbase + nt) * 16 + lr;
        float bv_ = biasAll[gn];
        #pragma unroll
        for (int r = 0; r < 4; ++r) {
            int grow = m0 + mrow + lg * 4 + r;
            unsigned short val = f2b(acc[nt][r] + bv_);
            if (gn < 64)       qout[(size_t)grow * HEAD + gn] = val;
            else if (gn < 128) kout[(size_t)grow * HEAD + gn - 64] = val;
            else {
                int t = (m0 & 4095) + mrow + lg * 4 + r;
                vtout[((size_t)bb * HEAD + gn - 128) * SEQ + t] = val;
            }
        }
    }
}

// ---------------- Kernel 2: flash attention, bf16 MFMA ----------------
// grid (SEQ/QBLK, BATCH, KS). block 256 (4 waves); wave w owns q rows [t0+16w, t0+16w+16).
__global__ __launch_bounds__(256, 4) void flashmm_kernel(
    const unsigned short* __restrict__ qb, const unsigned short* __restrict__ kb,
    const unsigned short* __restrict__ vt, const int* __restrict__ mask,
    float* __restrict__ opart, float* __restrict__ mpart, float* __restrict__ lpart,
    int nsplit)
{
    const int b  = blockIdx.y;
    const int t0 = blockIdx.x * QBLK;
    const int z  = blockIdx.z;
    const int tid  = threadIdx.x;
    const int lane = tid & 63;
    const int w    = tid >> 6;
    const int lr = lane & 15;
    const int lg = lane >> 4;
    const int span = SEQ / nsplit;
    const int s_begin = z * span, s_end = s_begin + span;

    __shared__ unsigned short ks_l[KT * HEAD];
    __shared__ unsigned short vt_l[HEAD * KT];
    __shared__ unsigned short ps_l[4][16 * KT];
    __shared__ int mk[KT];

    const unsigned short* qrow = qb + ((size_t)(b * SEQ + t0 + w * 16 + lr)) * HEAD;
    const short8 qf0 = *(const short8*)(qrow + lg * 8);
    const short8 qf1 = *(const short8*)(qrow + 32 + lg * 8);

    f32x4 acc_o[4];
    #pragma unroll
    for (int nt = 0; nt < 4; ++nt) acc_o[nt] = (f32x4){0.f, 0.f, 0.f, 0.f};
    float m_r[4] = {-INFINITY, -INFINITY, -INFINITY, -INFINITY};
    float l_r[4] = {0.f, 0.f, 0.f, 0.f};

    for (int st = s_begin; st < s_end; st += KT) {
        __syncthreads();
        #pragma unroll
        for (int i = 0; i < 2; ++i) {
            int c   = tid + i * 256;
            int row = c >> 3;
            int h0  = (c & 7) * 8;
            short8 gk = *(const short8*)(kb + ((size_t)(b * SEQ + st + row)) * HEAD + h0);
            *(short8*)&ks_l[row * HEAD + (h0 ^ ((row & 7) << 3))] = gk;
            short8 gv = *(const short8*)(vt + ((size_t)(b * HEAD + row)) * SEQ + st + h0);
            *(short8*)&vt_l[row * KT + (h0 ^ ((row & 7) << 3))] = gv;
        }
        if (tid < KT) mk[tid] = mask[(size_t)b * SEQ + st + tid];
        __syncthreads();

        f32x4 s_acc[4];
        #pragma unroll
        for (int ct = 0; ct < 4; ++ct) {
            int krow = ct * 16 + lr;
            short8 kf0 = *(const short8*)&ks_l[krow * HEAD + ((lg * 8) ^ ((krow & 7) << 3))];
            short8 kf1 = *(const short8*)&ks_l[krow * HEAD + ((32 + lg * 8) ^ ((krow & 7) << 3))];
            f32x4 zz = (f32x4){0.f, 0.f, 0.f, 0.f};
            zz = __builtin_amdgcn_mfma_f32_16x16x32_bf16(qf0, kf0, zz, 0, 0, 0);
            zz = __builtin_amdgcn_mfma_f32_16x16x32_bf16(qf1, kf1, zz, 0, 0, 0);
            s_acc[ct] = zz;
        }

        bool kp[4];
        #pragma unroll
        for (int ct = 0; ct < 4; ++ct) kp[ct] = (mk[ct * 16 + lr] != 0);

        float sf[4];
        #pragma unroll
        for (int r = 0; r < 4; ++r) {
            float v0 = kp[0] ? s_acc[0][r] : -1e9f;
            float v1 = kp[1] ? s_acc[1][r] : -1e9f;
            float v2 = kp[2] ? s_acc[2][r] : -1e9f;
            float v3 = kp[3] ? s_acc[3][r] : -1e9f;
            float mx = fmaxf(fmaxf(v0, v1), fmaxf(v2, v3));
            #pragma unroll
            for (int off = 1; off < 16; off <<= 1) mx = fmaxf(mx, __shfl_xor(mx, off));
            float mnew = fmaxf(m_r[r], mx);
            float p0 = __expf(v0 - mnew), p1 = __expf(v1 - mnew);
            float p2 = __expf(v2 - mnew), p3 = __expf(v3 - mnew);
            float rs = p0 + p1 + p2 + p3;
            #pragma unroll
            for (int off = 1; off < 16; off <<= 1) rs += __shfl_xor(rs, off);
            float sfr = __expf(m_r[r] - mnew);
            l_r[r] = l_r[r] * sfr + rs;
            m_r[r] = mnew;
            sf[r]  = sfr;
            int R = lg * 4 + r;
            unsigned short* pr = &ps_l[w][R * KT];
            int sw = (R & 7) << 3;
            pr[(0 * 16 + lr) ^ sw] = f2b(p0);
            pr[(1 * 16 + lr) ^ sw] = f2b(p1);
            pr[(2 * 16 + lr) ^ sw] = f2b(p2);
            pr[(3 * 16 + lr) ^ sw] = f2b(p3);
        }

        #pragma unroll
        for (int nt = 0; nt < 4; ++nt) {
            acc_o[nt][0] *= sf[0]; acc_o[nt][1] *= sf[1];
            acc_o[nt][2] *= sf[2]; acc_o[nt][3] *= sf[3];
        }

        #pragma unroll
        for (int kk = 0; kk < 2; ++kk) {
            int s0 = kk * 32 + lg * 8;
            short8 pf = *(const short8*)&ps_l[w][lr * KT + (s0 ^ ((lr & 7) << 3))];
            #pragma unroll
            for (int nt = 0; nt < 4; ++nt) {
                int hrow = nt * 16 + lr;
                short8 vf = *(const short8*)&vt_l[hrow * KT + (s0 ^ ((hrow & 7) << 3))];
                acc_o[nt] = __builtin_amdgcn_mfma_f32_16x16x32_bf16(pf, vf, acc_o[nt], 0, 0, 0);
            }
        }
    }

    const size_t rbase = (size_t)z * MROWS + (size_t)b * SEQ + t0 + w * 16;
    const size_t obase = rbase * HEAD;
    #pragma unroll
    for (int nt = 0; nt < 4; ++nt)
        #pragma unroll
        for (int r = 0; r < 4; ++r) {
            int R = lg * 4 + r;
            opart[obase + (size_t)R * HEAD + nt * 16 + lr] = acc_o[nt][r];
        }
    if (lr == 0) {
        #pragma unroll
        for (int r = 0; r < 4; ++r) {
            int R = lg * 4 + r;
            mpart[rbase + R] = m_r[r];
            lpart[rbase + R] = l_r[r];
        }
    }
}

// ---------------- Kernel 3: split combine + normalize ----------------
__global__ __launch_bounds__(256) void combine_kernel(
    const float* __restrict__ op, const float* __restrict__ mp,
    const float* __restrict__ lp, float* __restrict__ out, int nsplit)
{
    int idx = blockIdx.x * 256 + threadIdx.x;
    int row = idx >> 4;
    int h4  = (idx & 15) * 4;
    float mstar = -INFINITY;
    for (int s = 0; s < nsplit; ++s)
        mstar = fmaxf(mstar, mp[(size_t)s * MROWS + row]);
    float L = 0.f;
    float ax = 0.f, ay = 0.f, az = 0.f, aw = 0.f;
    for (int s = 0; s < nsplit; ++s) {
        float wgt = __expf(mp[(size_t)s * MROWS + row] - mstar);
        L += lp[(size_t)s * MROWS + row] * wgt;
        float4 o = *(const float4*)&op[((size_t)s * MROWS + row) * HEAD + h4];
        ax += o.x * wgt; ay += o.y * wgt; az += o.z * wgt; aw += o.w * wgt;
    }
    float r = 1.f / L;
    float4 res; res.x = ax * r; res.y = ay * r; res.z = az * r; res.w = aw * r;
    *(float4*)&out[(size_t)row * HEAD + h4] = res;
}

extern "C" void kernel_launch(void* const* d_in, const int* in_sizes, int n_in,
                              void* d_out, int out_size, void* d_ws, size_t ws_size,
                              hipStream_t stream) {
    const float* x    = (const float*)d_in[0];
    const int*   mask = (const int*)d_in[1];
    const float* wq   = (const float*)d_in[2];
    const float* bq   = (const float*)d_in[3];
    const float* wk   = (const float*)d_in[4];
    const float* bk   = (const float*)d_in[5];
    const float* wv   = (const float*)d_in[6];
    const float* bv   = (const float*)d_in[7];
    float* out = (float*)d_out;
    (void)in_sizes; (void)n_in; (void)out_size;

    const size_t NB = (size_t)MROWS * HEAD;       // 1,048,576 elements
    unsigned short* qw  = (unsigned short*)d_ws;  // bf16
    unsigned short* kw  = qw + NB;
    unsigned short* vtw = kw + NB;
    unsigned short* Wb  = vtw + NB;               // 192*1024 bf16
    float* biasAll = (float*)(Wb + (size_t)192 * DIM);
    float* mpart   = biasAll + 192;

    const size_t base = 3 * NB * 2 + (size_t)192 * DIM * 2 + 192 * 4;
    const size_t per  = (size_t)MROWS * 8 + NB * 4;
    int KS = 1;
    if (ws_size >= base + 4 * per) KS = 4;
    else if (ws_size >= base + 2 * per) KS = 2;

    float* lpart = mpart + (size_t)KS * MROWS;
    float* opart = lpart + (size_t)KS * MROWS;

    wconv_kernel<<<dim3(192), 256, 0, stream>>>(wq, bq, wk, bk, wv, bv, Wb, biasAll);
    qkvmm_kernel<<<dim3(MROWS / 32), 256, 0, stream>>>(x, Wb, biasAll, qw, kw, vtw);
    flashmm_kernel<<<dim3(SEQ / QBLK, BATCH, KS), 256, 0, stream>>>(qw, kw, vtw, mask,
                                                                    opart, mpart, lpart, KS);
    combine_kernel<<<dim3(MROWS * 16 / 256), 256, 0, stream>>>(opart, mpart, lpart, out, KS);
}

// Round 4
// 78.581 us; speedup vs baseline: 19.5539x; 1.2114x over previous
//
#include <hip/hip_runtime.h>
#include <math.h>

#define BATCH 4
#define SEQ   4096
#define DIM   1024
#define HEAD  64
#define MROWS (BATCH*SEQ)   // 16384
#define KT    64
#define QBLK  64

typedef __attribute__((ext_vector_type(8))) short short8;
typedef __attribute__((ext_vector_type(4))) short s16x4;
typedef __attribute__((ext_vector_type(4))) float f32x4;

static __device__ __forceinline__ unsigned short f2b(float f) {
    union { float f; unsigned u; } v; v.f = f;
    return (unsigned short)((v.u + 0x7FFFu + ((v.u >> 16) & 1u)) >> 16);
}

// ---------------- Kernel 0: weight convert fp32 -> bf16 [192][1024] ----------------
// q rows folded with 0.125 * log2(e)  (softmax runs in exp2 domain)
#define QSC (0.125f * 1.4426950408889634f)
__global__ __launch_bounds__(256) void wconv_kernel(
    const float* __restrict__ wq, const float* __restrict__ bq,
    const float* __restrict__ wk, const float* __restrict__ bk,
    const float* __restrict__ wv, const float* __restrict__ bv,
    unsigned short* __restrict__ Wb, float* __restrict__ biasAll)
{
    int idx = blockIdx.x * 256 + threadIdx.x;
    int e   = idx * 4;
    int row = e >> 10;
    int col = e & 1023;
    const float* src = (row < 64) ? wq : (row < 128) ? wk : wv;
    float s = (row < 64) ? QSC : 1.0f;
    float4 g = *(const float4*)&src[(size_t)(row & 63) * DIM + col];
    ushort4 o;
    o.x = f2b(g.x * s); o.y = f2b(g.y * s); o.z = f2b(g.z * s); o.w = f2b(g.w * s);
    *(ushort4*)&Wb[e] = o;
    if (idx < 192) {
        const float* bs = (idx < 64) ? bq : (idx < 128) ? bk : bv;
        biasAll[idx] = bs[idx & 63] * ((idx < 64) ? QSC : 1.0f);
    }
}

// ---------------- Kernel 1: fused QKV projection, bf16 MFMA ----------------
#define NIT (DIM / 32)
__global__ __launch_bounds__(256) void qkvmm_kernel(
    const float* __restrict__ x, const unsigned short* __restrict__ Wb,
    const float* __restrict__ biasAll,
    unsigned short* __restrict__ qout, unsigned short* __restrict__ kout,
    unsigned short* __restrict__ vtout)
{
    __shared__ unsigned short xs[2][32 * 32];
    __shared__ unsigned short ws[2][192 * 32];

    const int tid  = threadIdx.x;
    const int m0   = blockIdx.x * 32;
    const int bb   = m0 >> 12;
    const int lane = tid & 63;
    const int w    = tid >> 6;
    const int lr   = lane & 15;
    const int lg   = lane >> 4;
    const int mrow  = (w >> 1) * 16;
    const int nbase = (w & 1) * 6;

    const int sxrow = tid >> 2, sxlg = tid & 3;
    int wn[3], wlg[3];
    #pragma unroll
    for (int i = 0; i < 3; ++i) { int idx = tid + i * 256; wn[i] = idx >> 2; wlg[i] = idx & 3; }

    f32x4 acc[6];
    #pragma unroll
    for (int nt = 0; nt < 6; ++nt) acc[nt] = (f32x4){0.f, 0.f, 0.f, 0.f};

    float4 xg0, xg1;
    short8 wg[3];

    auto LOADR = [&](int ko) {
        if (tid < 128) {
            const float* xp = &x[(size_t)(m0 + sxrow) * DIM + ko + sxlg * 8];
            xg0 = *(const float4*)xp;
            xg1 = *(const float4*)(xp + 4);
        }
        #pragma unroll
        for (int i = 0; i < 3; ++i)
            wg[i] = *(const short8*)&Wb[(size_t)wn[i] * DIM + ko + wlg[i] * 8];
    };
    auto WRITE = [&](int buf) {
        if (tid < 128) {
            short8 c;
            c[0] = (short)f2b(xg0.x); c[1] = (short)f2b(xg0.y);
            c[2] = (short)f2b(xg0.z); c[3] = (short)f2b(xg0.w);
            c[4] = (short)f2b(xg1.x); c[5] = (short)f2b(xg1.y);
            c[6] = (short)f2b(xg1.z); c[7] = (short)f2b(xg1.w);
            *(short8*)&xs[buf][sxrow * 32 + ((sxlg * 8) ^ ((sxrow & 3) * 8))] = c;
        }
        #pragma unroll
        for (int i = 0; i < 3; ++i)
            *(short8*)&ws[buf][wn[i] * 32 + ((wlg[i] * 8) ^ ((wn[i] & 3) * 8))] = wg[i];
    };

    LOADR(0);
    WRITE(0);
    __syncthreads();

    for (int it = 0; it < NIT; ++it) {
        if (it + 1 < NIT) LOADR((it + 1) * 32);
        const int cur = it & 1;
        const int arow = mrow + lr;
        short8 af = *(const short8*)&xs[cur][arow * 32 + ((lg * 8) ^ ((arow & 3) * 8))];
        #pragma unroll
        for (int nt = 0; nt < 6; ++nt) {
            int n = (nbase + nt) * 16 + lr;
            short8 bf = *(const short8*)&ws[cur][n * 32 + ((lg * 8) ^ ((n & 3) * 8))];
            acc[nt] = __builtin_amdgcn_mfma_f32_16x16x32_bf16(af, bf, acc[nt], 0, 0, 0);
        }
        if (it + 1 < NIT) WRITE((it + 1) & 1);
        __syncthreads();
    }

    #pragma unroll
    for (int nt = 0; nt < 6; ++nt) {
        int gn = (nbase + nt) * 16 + lr;
        float bv_ = biasAll[gn];
        #pragma unroll
        for (int r = 0; r < 4; ++r) {
            int grow = m0 + mrow + lg * 4 + r;
            unsigned short val = f2b(acc[nt][r] + bv_);
            if (gn < 64)       qout[(size_t)grow * HEAD + gn] = val;
            else if (gn < 128) kout[(size_t)grow * HEAD + gn - 64] = val;
            else {
                int t = (m0 & 4095) + mrow + lg * 4 + r;
                vtout[((size_t)bb * HEAD + gn - 128) * SEQ + t] = val;
            }
        }
    }
}

// ---------------- Kernel 2: flash attention, swapped-QK^T bf16 MFMA ----------------
// grid (SEQ/QBLK, BATCH, KS), block 256 (4 waves). Lane owns q-row lr, keys lg-sliced.
__global__ __launch_bounds__(256, 4) void flashmm_kernel(
    const unsigned short* __restrict__ qb, const unsigned short* __restrict__ kb,
    const unsigned short* __restrict__ vt, const int* __restrict__ mask,
    float* __restrict__ opart, float* __restrict__ mpart, float* __restrict__ lpart,
    int nsplit)
{
    const int b  = blockIdx.y;
    const int t0 = blockIdx.x * QBLK;
    const int z  = blockIdx.z;
    const int tid  = threadIdx.x;
    const int lane = tid & 63;
    const int w    = tid >> 6;
    const int lr = lane & 15;
    const int lg = lane >> 4;
    const int span = SEQ / nsplit;
    const int s_begin = z * span, s_end = s_begin + span;

    __shared__ unsigned short ks_l[KT * HEAD];
    __shared__ unsigned short vt_l[HEAD * KT];
    __shared__ unsigned short ps_l[4][16 * KT];
    __shared__ float mkf[KT];
    __shared__ float sf_l[4][16];

    // Q fragment (B operand): lane lr -> q row, lg -> h chunk
    const unsigned short* qrow = qb + ((size_t)(b * SEQ + t0 + w * 16 + lr)) * HEAD;
    const short8 qf0 = *(const short8*)(qrow + lg * 8);
    const short8 qf1 = *(const short8*)(qrow + 32 + lg * 8);

    f32x4 acc_o[4];
    #pragma unroll
    for (int nt = 0; nt < 4; ++nt) acc_o[nt] = (f32x4){0.f, 0.f, 0.f, 0.f};
    float m_r = -INFINITY, l_r = 0.f;

    // staging registers (T14 issue-early / write-late)
    short8 kg[2], vg[2];
    float mgf = 0.f;

    auto LOADR = [&](int st) {
        #pragma unroll
        for (int i = 0; i < 2; ++i) {
            int c   = tid + i * 256;
            int row = c >> 3;
            int h0  = (c & 7) * 8;
            kg[i] = *(const short8*)(kb + ((size_t)(b * SEQ + st + row)) * HEAD + h0);
            vg[i] = *(const short8*)(vt + ((size_t)(b * HEAD + row)) * SEQ + st + h0);
        }
        if (tid < KT) mgf = (mask[(size_t)b * SEQ + st + tid] != 0) ? 0.f : -1e9f;
    };
    auto WRITE = [&]() {
        #pragma unroll
        for (int i = 0; i < 2; ++i) {
            int c   = tid + i * 256;
            int row = c >> 3;
            int h0  = (c & 7) * 8;
            *(short8*)&ks_l[row * HEAD + (h0 ^ ((row & 7) << 3))] = kg[i];
            *(short8*)&vt_l[row * KT + (h0 ^ ((row & 7) << 3))] = vg[i];
        }
        if (tid < KT) mkf[tid] = mgf;
    };

    LOADR(s_begin);
    for (int st = s_begin; st < s_end; st += KT) {
        __syncthreads();           // previous compute done with LDS
        WRITE();
        __syncthreads();           // tile ready
        if (st + KT < s_end) LOADR(st + KT);

        // ---- QK^T swapped: A = K rows, B = Q. D: col(lr)=q-row, row=key ----
        f32x4 sT[4];
        __builtin_amdgcn_s_setprio(1);
        #pragma unroll
        for (int ct = 0; ct < 4; ++ct) {
            int krow = ct * 16 + lr;
            short8 kf0 = *(const short8*)&ks_l[krow * HEAD + ((lg * 8) ^ ((krow & 7) << 3))];
            short8 kf1 = *(const short8*)&ks_l[krow * HEAD + ((32 + lg * 8) ^ ((krow & 7) << 3))];
            f32x4 zz = (f32x4){0.f, 0.f, 0.f, 0.f};
            zz = __builtin_amdgcn_mfma_f32_16x16x32_bf16(kf0, qf0, zz, 0, 0, 0);
            zz = __builtin_amdgcn_mfma_f32_16x16x32_bf16(kf1, qf1, zz, 0, 0, 0);
            sT[ct] = zz;
        }
        __builtin_amdgcn_s_setprio(0);

        // ---- additive mask bias, in-lane over this lane's 16 keys ----
        #pragma unroll
        for (int ct = 0; ct < 4; ++ct) {
            f32x4 mb = *(const f32x4*)&mkf[ct * 16 + lg * 4];
            sT[ct][0] += mb[0]; sT[ct][1] += mb[1];
            sT[ct][2] += mb[2]; sT[ct][3] += mb[3];
        }

        // ---- softmax for q-row lr (16 in-lane values + 2 shfl) ----
        float mx = sT[0][0];
        #pragma unroll
        for (int ct = 0; ct < 4; ++ct)
            #pragma unroll
            for (int r = 0; r < 4; ++r) mx = fmaxf(mx, sT[ct][r]);
        mx = fmaxf(mx, __shfl_xor(mx, 16));
        mx = fmaxf(mx, __shfl_xor(mx, 32));
        float mnew = fmaxf(m_r, mx);

        float rs = 0.f;
        #pragma unroll
        for (int ct = 0; ct < 4; ++ct)
            #pragma unroll
            for (int r = 0; r < 4; ++r) {
                float p = __builtin_amdgcn_exp2f(sT[ct][r] - mnew);
                sT[ct][r] = p;
                rs += p;
            }
        rs += __shfl_xor(rs, 16);
        rs += __shfl_xor(rs, 32);
        float sf = __builtin_amdgcn_exp2f(m_r - mnew);
        l_r = l_r * sf + rs;
        m_r = mnew;
        if (lg == 0) sf_l[w][lr] = sf;    // wave-local, no barrier needed

        // ---- pack P (4 consecutive keys per b64) into wave-local LDS ----
        #pragma unroll
        for (int ct = 0; ct < 4; ++ct) {
            s16x4 pk;
            pk[0] = (short)f2b(sT[ct][0]); pk[1] = (short)f2b(sT[ct][1]);
            pk[2] = (short)f2b(sT[ct][2]); pk[3] = (short)f2b(sT[ct][3]);
            *(s16x4*)&ps_l[w][lr * KT + ((ct * 16 + lg * 4) ^ ((lr & 7) << 3))] = pk;
        }

        // ---- rescale O accumulators (rows lg*4+r need sf from lanes lg*4+r) ----
        f32x4 sfv = *(const f32x4*)&sf_l[w][lg * 4];
        #pragma unroll
        for (int nt = 0; nt < 4; ++nt) {
            acc_o[nt][0] *= sfv[0]; acc_o[nt][1] *= sfv[1];
            acc_o[nt][2] *= sfv[2]; acc_o[nt][3] *= sfv[3];
        }

        // ---- PV: A = P [16 x KT], B = V^T rows ----
        __builtin_amdgcn_s_setprio(1);
        #pragma unroll
        for (int kk = 0; kk < 2; ++kk) {
            int s0 = kk * 32 + lg * 8;
            short8 pf = *(const short8*)&ps_l[w][lr * KT + (s0 ^ ((lr & 7) << 3))];
            #pragma unroll
            for (int nt = 0; nt < 4; ++nt) {
                int hrow = nt * 16 + lr;
                short8 vf = *(const short8*)&vt_l[hrow * KT + (s0 ^ ((hrow & 7) << 3))];
                acc_o[nt] = __builtin_amdgcn_mfma_f32_16x16x32_bf16(pf, vf, acc_o[nt], 0, 0, 0);
            }
        }
        __builtin_amdgcn_s_setprio(0);
    }

    // ---- write unnormalized partials ----
    const size_t rbase = (size_t)z * MROWS + (size_t)b * SEQ + t0 + w * 16;
    const size_t obase = rbase * HEAD;
    #pragma unroll
    for (int nt = 0; nt < 4; ++nt)
        #pragma unroll
        for (int r = 0; r < 4; ++r) {
            int R = lg * 4 + r;
            opart[obase + (size_t)R * HEAD + nt * 16 + lr] = acc_o[nt][r];
        }
    if (lg == 0) {
        mpart[rbase + lr] = m_r;
        lpart[rbase + lr] = l_r;
    }
}

// ---------------- Kernel 3: split combine + normalize (exp2 domain) ----------------
__global__ __launch_bounds__(256) void combine_kernel(
    const float* __restrict__ op, const float* __restrict__ mp,
    const float* __restrict__ lp, float* __restrict__ out, int nsplit)
{
    int idx = blockIdx.x * 256 + threadIdx.x;
    int row = idx >> 4;
    int h4  = (idx & 15) * 4;
    float mstar = -INFINITY;
    for (int s = 0; s < nsplit; ++s)
        mstar = fmaxf(mstar, mp[(size_t)s * MROWS + row]);
    float L = 0.f;
    float ax = 0.f, ay = 0.f, az = 0.f, aw = 0.f;
    for (int s = 0; s < nsplit; ++s) {
        float wgt = __builtin_amdgcn_exp2f(mp[(size_t)s * MROWS + row] - mstar);
        L += lp[(size_t)s * MROWS + row] * wgt;
        float4 o = *(const float4*)&op[((size_t)s * MROWS + row) * HEAD + h4];
        ax += o.x * wgt; ay += o.y * wgt; az += o.z * wgt; aw += o.w * wgt;
    }
    float r = 1.f / L;
    float4 res; res.x = ax * r; res.y = ay * r; res.z = az * r; res.w = aw * r;
    *(float4*)&out[(size_t)row * HEAD + h4] = res;
}

extern "C" void kernel_launch(void* const* d_in, const int* in_sizes, int n_in,
                              void* d_out, int out_size, void* d_ws, size_t ws_size,
                              hipStream_t stream) {
    const float* x    = (const float*)d_in[0];
    const int*   mask = (const int*)d_in[1];
    const float* wq   = (const float*)d_in[2];
    const float* bq   = (const float*)d_in[3];
    const float* wk   = (const float*)d_in[4];
    const float* bk   = (const float*)d_in[5];
    const float* wv   = (const float*)d_in[6];
    const float* bv   = (const float*)d_in[7];
    float* out = (float*)d_out;
    (void)in_sizes; (void)n_in; (void)out_size;

    const size_t NB = (size_t)MROWS * HEAD;
    unsigned short* qw  = (unsigned short*)d_ws;
    unsigned short* kw  = qw + NB;
    unsigned short* vtw = kw + NB;
    unsigned short* Wb  = vtw + NB;
    float* biasAll = (float*)(Wb + (size_t)192 * DIM);
    float* mpart   = biasAll + 192;

    const size_t base = 3 * NB * 2 + (size_t)192 * DIM * 2 + 192 * 4;
    const size_t per  = (size_t)MROWS * 8 + NB * 4;
    int KS = 1;
    if      (ws_size >= base + 8 * per) KS = 8;
    else if (ws_size >= base + 4 * per) KS = 4;
    else if (ws_size >= base + 2 * per) KS = 2;

    float* lpart = mpart + (size_t)KS * MROWS;
    float* opart = lpart + (size_t)KS * MROWS;

    wconv_kernel<<<dim3(192), 256, 0, stream>>>(wq, bq, wk, bk, wv, bv, Wb, biasAll);
    qkvmm_kernel<<<dim3(MROWS / 32), 256, 0, stream>>>(x, Wb, biasAll, qw, kw, vtw);
    flashmm_kernel<<<dim3(SEQ / QBLK, BATCH, KS), 256, 0, stream>>>(qw, kw, vtw, mask,
                                                                    opart, mpart, lpart, KS);
    combine_kernel<<<dim3(MROWS * 16 / 256), 256, 0, stream>>>(opart, mpart, lpart, out, KS);
}